// Round 3
// baseline (340.838 us; speedup 1.0000x reference)
//
#include <hip/hip_runtime.h>
#include <hip/hip_bf16.h>

#define B_N 8192
#define M_N 3129
#define M_PAD 3200
#define D_N 512

#define GLOBAL_AS __attribute__((address_space(1)))
#define LDS_AS __attribute__((address_space(3)))

typedef __bf16 bf16x8 __attribute__((ext_vector_type(8)));
typedef float f32x4 __attribute__((ext_vector_type(4)));

// ---------------------------------------------------------------------------
// Fused prep: normalize mm_proj -> g (blocks 0..2047), normalize ans_emb -> a
// with zero-padding to M_PAD (blocks 2048..2847), obj cosine rows
// (blocks 2848..4895). One wave per row everywhere; one dispatch total.
#define PREP_G_BLOCKS   (B_N / 4)      // 2048
#define PREP_A_BLOCKS   (M_PAD / 4)    // 800
#define PREP_OBJ_BLOCKS (B_N / 4)      // 2048

__device__ __forceinline__ void normalize_row(
    const float* __restrict__ x, __bf16* __restrict__ y,
    int row, int nrows_src, int lane) {
  bf16x8 out;
  if (row >= nrows_src) {
    for (int j = 0; j < 8; ++j) out[j] = (__bf16)0.0f;
    *(bf16x8*)(y + (size_t)row * D_N + lane * 8) = out;
    return;
  }
  const float4* xr = (const float4*)(x + (size_t)row * D_N);
  float4 v0 = xr[lane * 2], v1 = xr[lane * 2 + 1];
  float s = v0.x*v0.x + v0.y*v0.y + v0.z*v0.z + v0.w*v0.w
          + v1.x*v1.x + v1.y*v1.y + v1.z*v1.z + v1.w*v1.w;
  for (int o = 1; o < 64; o <<= 1) s += __shfl_xor(s, o);
  float rn = 1.0f / fmaxf(sqrtf(s), 1e-8f);
  float vals[8] = {v0.x, v0.y, v0.z, v0.w, v1.x, v1.y, v1.z, v1.w};
  for (int j = 0; j < 8; ++j) out[j] = (__bf16)(vals[j] * rn);
  *(bf16x8*)(y + (size_t)row * D_N + lane * 8) = out;
}

__global__ __launch_bounds__(256) void prep_kernel(
    const float* __restrict__ mm_proj, const float* __restrict__ ans_emb,
    const float* __restrict__ v_max, const float* __restrict__ mm,
    __bf16* __restrict__ g, __bf16* __restrict__ a,
    float* __restrict__ obj) {
  int blk = blockIdx.x;
  int wid = threadIdx.x >> 6, lane = threadIdx.x & 63;
  if (blk < PREP_G_BLOCKS) {
    normalize_row(mm_proj, g, blk * 4 + wid, B_N, lane);
  } else if (blk < PREP_G_BLOCKS + PREP_A_BLOCKS) {
    normalize_row(ans_emb, a, (blk - PREP_G_BLOCKS) * 4 + wid, M_N, lane);
  } else {
    int b = (blk - PREP_G_BLOCKS - PREP_A_BLOCKS) * 4 + wid;
    const float4* vr = (const float4*)(v_max + (size_t)b * D_N);
    const float4* mr = (const float4*)(mm + (size_t)b * D_N);
    float4 a0 = vr[lane * 2], a1 = vr[lane * 2 + 1];
    float4 b0 = mr[lane * 2], b1 = mr[lane * 2 + 1];
    float sv = a0.x*a0.x + a0.y*a0.y + a0.z*a0.z + a0.w*a0.w
             + a1.x*a1.x + a1.y*a1.y + a1.z*a1.z + a1.w*a1.w;
    float sm = b0.x*b0.x + b0.y*b0.y + b0.z*b0.z + b0.w*b0.w
             + b1.x*b1.x + b1.y*b1.y + b1.z*b1.z + b1.w*b1.w;
    float sd = a0.x*b0.x + a0.y*b0.y + a0.z*b0.z + a0.w*b0.w
             + a1.x*b1.x + a1.y*b1.y + a1.z*b1.z + a1.w*b1.w;
    for (int o = 1; o < 64; o <<= 1) {
      sv += __shfl_xor(sv, o);
      sm += __shfl_xor(sm, o);
      sd += __shfl_xor(sd, o);
    }
    if (lane == 0) {
      float dist = sd / (fmaxf(sqrtf(sv), 1e-8f) * fmaxf(sqrtf(sm), 1e-8f));
      obj[b] = 1.0f - dist;
    }
  }
}

// ---------------------------------------------------------------------------
// Fused cosine-GEMM + exp row-sum + positive gather.
// den[b] += sum_m exp(dot(g[b], a[m])); pos[b] = d_logit[b][cid[b]] (the
// unique epilogue element with m == cid[b] writes it — exactly one writer).
// 128x128 tile, K=512 in steps of 32, global_load_lds width-16 staging,
// mfma_f32_16x16x32_bf16, 2x2 waves each computing 64x64 (4x4 MFMA tiles).
__global__ __launch_bounds__(256) void nce_gemm_kernel(
    const __bf16* __restrict__ g, const __bf16* __restrict__ a,
    const int* __restrict__ cid,
    float* __restrict__ den, float* __restrict__ pos) {
  __shared__ __bf16 As[128 * 32];
  __shared__ __bf16 Bs[128 * 32];
  const int t = threadIdx.x;
  const int mtile = blockIdx.x;   // 0..24
  const int btile = blockIdx.y;   // 0..63
  const int brow0 = btile * 128;
  const int mrow0 = mtile * 128;
  const int lane = t & 63;
  const int wid = t >> 6;
  const int wrow = wid >> 1;      // 0..1
  const int wcol = wid & 1;       // 0..1
  const int r = lane & 15;
  const int quad = lane >> 4;

  f32x4 acc[4][4];
  for (int i = 0; i < 4; ++i)
    for (int j = 0; j < 4; ++j)
      acc[i][j] = f32x4{0.f, 0.f, 0.f, 0.f};

  for (int k0 = 0; k0 < D_N; k0 += 32) {
    __syncthreads();  // previous iteration's ds_reads done before overwrite
    for (int i = 0; i < 2; ++i) {
      int s = t + i * 256;
      int row = s >> 2;
      int kq = (s & 3) << 3;
      const __bf16* ga = g + (size_t)(brow0 + row) * D_N + (k0 + kq);
      __builtin_amdgcn_global_load_lds((const GLOBAL_AS void*)ga,
                                       (LDS_AS void*)(As + s * 8), 16, 0, 0);
      const __bf16* gb = a + (size_t)(mrow0 + row) * D_N + (k0 + kq);
      __builtin_amdgcn_global_load_lds((const GLOBAL_AS void*)gb,
                                       (LDS_AS void*)(Bs + s * 8), 16, 0, 0);
    }
    __syncthreads();
    bf16x8 af[4], bf[4];
    for (int i = 0; i < 4; ++i)
      af[i] = *(const bf16x8*)(As + (wrow * 64 + i * 16 + r) * 32 + quad * 8);
    for (int j = 0; j < 4; ++j)
      bf[j] = *(const bf16x8*)(Bs + (wcol * 64 + j * 16 + r) * 32 + quad * 8);
    for (int i = 0; i < 4; ++i)
      for (int j = 0; j < 4; ++j)
        acc[i][j] = __builtin_amdgcn_mfma_f32_16x16x32_bf16(af[i], bf[j],
                                                            acc[i][j], 0, 0, 0);
  }

  // Epilogue: C/D layout is col = lane&15, row = quad*4 + reg.
  for (int i = 0; i < 4; ++i) {
    for (int reg = 0; reg < 4; ++reg) {
      int b = brow0 + wrow * 64 + i * 16 + quad * 4 + reg;
      int cid_b = cid[b];
      float s = 0.0f;
      for (int j = 0; j < 4; ++j) {
        int m = mrow0 + wcol * 64 + j * 16 + r;
        float v = acc[i][j][reg];
        if (m < M_N) s += __expf(v);
        if (m == cid_b) pos[b] = v;   // exactly one (block,lane,j) matches
      }
      s += __shfl_xor(s, 1);
      s += __shfl_xor(s, 2);
      s += __shfl_xor(s, 4);
      s += __shfl_xor(s, 8);
      if (r == 0) atomicAdd(den + b, s);  // 25 adders per address — low contention
    }
  }
}

// ---------------------------------------------------------------------------
// Cross-entropy, one block per row. All body loads issued UPFRONT (6
// unconditional + 2 clamped dwordx4 per thread = 128 B in flight) — the
// round-2 rolled loop only kept ~32 B in flight per wave and was
// latency-bound at 1.4 TB/s. Rows are 3129 floats; row base mod 4 == b&3,
// scalar head h brings us to a 16B boundary; n4 in {781, 782} so indices
// t, t+256, t+512 are always valid and t+768 valid for <=14 threads.
__global__ __launch_bounds__(256) void ce_kernel(
    const float* __restrict__ lq, const float* __restrict__ lr,
    const int* __restrict__ cid,
    float* __restrict__ ce_q, float* __restrict__ ce_r) {
  int b = blockIdx.x;
  const float* rq = lq + (size_t)b * M_N;
  const float* rr = lr + (size_t)b * M_N;
  int t = threadIdx.x;
  int mis = b & 3;                 // (b*3129)&3 == b&3 since 3129%4==1
  int h = (4 - mis) & 3;           // scalar head count
  int n4 = (M_N - h) >> 2;         // 781 or 782
  int tail0 = h + (n4 << 2);
  int ntail = M_N - tail0;         // 0..3
  const float4* q4 = (const float4*)(rq + h);
  const float4* r4 = (const float4*)(rr + h);
  bool has3 = (t + 768) < n4;
  int i3 = has3 ? (t + 768) : (n4 - 1);
  float4 q0 = q4[t], q1 = q4[t + 256], q2 = q4[t + 512], q3 = q4[i3];
  float4 p0 = r4[t], p1 = r4[t + 256], p2 = r4[t + 512], p3 = r4[i3];
  float sq = __expf(q0.x) + __expf(q0.y) + __expf(q0.z) + __expf(q0.w)
           + __expf(q1.x) + __expf(q1.y) + __expf(q1.z) + __expf(q1.w)
           + __expf(q2.x) + __expf(q2.y) + __expf(q2.z) + __expf(q2.w);
  float sr = __expf(p0.x) + __expf(p0.y) + __expf(p0.z) + __expf(p0.w)
           + __expf(p1.x) + __expf(p1.y) + __expf(p1.z) + __expf(p1.w)
           + __expf(p2.x) + __expf(p2.y) + __expf(p2.z) + __expf(p2.w);
  if (has3) {
    sq += __expf(q3.x) + __expf(q3.y) + __expf(q3.z) + __expf(q3.w);
    sr += __expf(p3.x) + __expf(p3.y) + __expf(p3.z) + __expf(p3.w);
  }
  if (t < h) { sq += __expf(rq[t]); sr += __expf(rr[t]); }
  if (t >= 64 && t < 64 + ntail) {
    int i = tail0 + (t - 64);
    sq += __expf(rq[i]); sr += __expf(rr[i]);
  }
  for (int o = 1; o < 64; o <<= 1) {
    sq += __shfl_xor(sq, o);
    sr += __shfl_xor(sr, o);
  }
  __shared__ float ssq[4], ssr[4];
  int wid = t >> 6;
  if ((t & 63) == 0) { ssq[wid] = sq; ssr[wid] = sr; }
  __syncthreads();
  if (t == 0) {
    float tq = ssq[0] + ssq[1] + ssq[2] + ssq[3];
    float tr = ssr[0] + ssr[1] + ssr[2] + ssr[3];
    int label = cid[b];
    ce_q[b] = logf(tq) - rq[label];
    ce_r[b] = logf(tr) - rr[label];
  }
}

// ---------------------------------------------------------------------------
// Final assembly: nce = mean(log(den) - pos); means of per-row CE/obj arrays.
__global__ __launch_bounds__(256) void final_kernel(
    const float* __restrict__ den, const float* __restrict__ pos,
    const float* __restrict__ ce_q, const float* __restrict__ ce_r,
    const float* __restrict__ obj, float* __restrict__ out) {
  int t = threadIdx.x;
  float s_nce = 0.0f, s_ceq = 0.0f, s_cer = 0.0f, s_obj = 0.0f;
  for (int b = t; b < B_N; b += 256) {
    s_nce += logf(den[b]) - pos[b];
    s_ceq += ce_q[b];
    s_cer += ce_r[b];
    s_obj += obj[b];
  }
  for (int o = 1; o < 64; o <<= 1) {
    s_nce += __shfl_xor(s_nce, o);
    s_ceq += __shfl_xor(s_ceq, o);
    s_cer += __shfl_xor(s_cer, o);
    s_obj += __shfl_xor(s_obj, o);
  }
  __shared__ float red[4][4];
  int wid = t >> 6;
  if ((t & 63) == 0) {
    red[wid][0] = s_nce; red[wid][1] = s_ceq;
    red[wid][2] = s_cer; red[wid][3] = s_obj;
  }
  __syncthreads();
  if (t == 0) {
    float nce = (red[0][0] + red[1][0] + red[2][0] + red[3][0]) / (float)B_N;
    float ceq = (red[0][1] + red[1][1] + red[2][1] + red[3][1]) / (float)B_N;
    float cer = (red[0][2] + red[1][2] + red[2][2] + red[3][2]) / (float)B_N;
    float ob  = (red[0][3] + red[1][3] + red[2][3] + red[3][3]) / (float)B_N;
    float fusion = (cer + ob + nce) * (1.0f / 3.0f);
    float loss = fusion + ceq;  // question_loss_weight = 1.0
    out[0] = loss;
    out[1] = fusion;
    out[2] = ceq;
  }
}

// ---------------------------------------------------------------------------
extern "C" void kernel_launch(void* const* d_in, const int* in_sizes, int n_in,
                              void* d_out, int out_size, void* d_ws, size_t ws_size,
                              hipStream_t stream) {
  const float* mm_proj     = (const float*)d_in[0];
  const float* ans_emb     = (const float*)d_in[1];
  const float* v_max       = (const float*)d_in[2];
  const float* mm          = (const float*)d_in[3];
  const float* logits_q    = (const float*)d_in[4];
  const float* logits_rubi = (const float*)d_in[5];
  const int*   cid         = (const int*)d_in[6];
  float* out = (float*)d_out;

  // Workspace layout (all 16B-aligned):
  //   g_bf16 : 8192*512*2  = 8,388,608 B
  //   a_bf16 : 3200*512*2  = 3,276,800 B
  //   den, pos, ce_q, ce_r, obj : 8192 floats each
  char* ws = (char*)d_ws;
  __bf16* g = (__bf16*)ws;
  __bf16* a = (__bf16*)(ws + 8388608);
  float* den  = (float*)(ws + 8388608 + 3276800);
  float* pos  = den + B_N;
  float* ce_q = pos + B_N;
  float* ce_r = ce_q + B_N;
  float* obj  = ce_r + B_N;

  // den accumulates via atomics — zero it (ws is poisoned 0xAA every launch).
  hipMemsetAsync(den, 0, (size_t)B_N * sizeof(float), stream);

  prep_kernel<<<PREP_G_BLOCKS + PREP_A_BLOCKS + PREP_OBJ_BLOCKS, 256, 0,
                stream>>>(mm_proj, ans_emb, v_max, mm, g, a, obj);
  nce_gemm_kernel<<<dim3(M_PAD / 128, B_N / 128), 256, 0, stream>>>(
      g, a, cid, den, pos);
  ce_kernel<<<B_N, 256, 0, stream>>>(logits_q, logits_rubi, cid, ce_q, ce_r);
  final_kernel<<<1, 256, 0, stream>>>(den, pos, ce_q, ce_r, obj, out);
}

// Round 4
// 325.097 us; speedup vs baseline: 1.0484x; 1.0484x over previous
//
#include <hip/hip_runtime.h>
#include <hip/hip_bf16.h>

#define B_N 8192
#define M_N 3129
#define M_PAD 3200
#define D_N 512

#define GLOBAL_AS __attribute__((address_space(1)))
#define LDS_AS __attribute__((address_space(3)))

typedef __bf16 bf16x8 __attribute__((ext_vector_type(8)));
typedef float f32x4 __attribute__((ext_vector_type(4)));

// ---------------------------------------------------------------------------
// Fused prep: normalize mm_proj -> g, normalize ans_emb -> a (zero-padded to
// M_PAD), obj cosine rows. One wave per row; one dispatch.
#define PREP_G_BLOCKS   (B_N / 4)      // 2048
#define PREP_A_BLOCKS   (M_PAD / 4)    // 800
#define PREP_OBJ_BLOCKS (B_N / 4)      // 2048

__device__ __forceinline__ void normalize_row(
    const float* __restrict__ x, __bf16* __restrict__ y,
    int row, int nrows_src, int lane) {
  bf16x8 out;
  if (row >= nrows_src) {
    for (int j = 0; j < 8; ++j) out[j] = (__bf16)0.0f;
    *(bf16x8*)(y + (size_t)row * D_N + lane * 8) = out;
    return;
  }
  const float4* xr = (const float4*)(x + (size_t)row * D_N);
  float4 v0 = xr[lane * 2], v1 = xr[lane * 2 + 1];
  float s = v0.x*v0.x + v0.y*v0.y + v0.z*v0.z + v0.w*v0.w
          + v1.x*v1.x + v1.y*v1.y + v1.z*v1.z + v1.w*v1.w;
  for (int o = 1; o < 64; o <<= 1) s += __shfl_xor(s, o);
  float rn = 1.0f / fmaxf(sqrtf(s), 1e-8f);
  float vals[8] = {v0.x, v0.y, v0.z, v0.w, v1.x, v1.y, v1.z, v1.w};
  for (int j = 0; j < 8; ++j) out[j] = (__bf16)(vals[j] * rn);
  *(bf16x8*)(y + (size_t)row * D_N + lane * 8) = out;
}

__global__ __launch_bounds__(256) void prep_kernel(
    const float* __restrict__ mm_proj, const float* __restrict__ ans_emb,
    const float* __restrict__ v_max, const float* __restrict__ mm,
    __bf16* __restrict__ g, __bf16* __restrict__ a,
    float* __restrict__ obj) {
  int blk = blockIdx.x;
  int wid = threadIdx.x >> 6, lane = threadIdx.x & 63;
  if (blk < PREP_G_BLOCKS) {
    normalize_row(mm_proj, g, blk * 4 + wid, B_N, lane);
  } else if (blk < PREP_G_BLOCKS + PREP_A_BLOCKS) {
    normalize_row(ans_emb, a, (blk - PREP_G_BLOCKS) * 4 + wid, M_N, lane);
  } else {
    int b = (blk - PREP_G_BLOCKS - PREP_A_BLOCKS) * 4 + wid;
    const float4* vr = (const float4*)(v_max + (size_t)b * D_N);
    const float4* mr = (const float4*)(mm + (size_t)b * D_N);
    float4 a0 = vr[lane * 2], a1 = vr[lane * 2 + 1];
    float4 b0 = mr[lane * 2], b1 = mr[lane * 2 + 1];
    float sv = a0.x*a0.x + a0.y*a0.y + a0.z*a0.z + a0.w*a0.w
             + a1.x*a1.x + a1.y*a1.y + a1.z*a1.z + a1.w*a1.w;
    float sm = b0.x*b0.x + b0.y*b0.y + b0.z*b0.z + b0.w*b0.w
             + b1.x*b1.x + b1.y*b1.y + b1.z*b1.z + b1.w*b1.w;
    float sd = a0.x*b0.x + a0.y*b0.y + a0.z*b0.z + a0.w*b0.w
             + a1.x*b1.x + a1.y*b1.y + a1.z*b1.z + a1.w*b1.w;
    for (int o = 1; o < 64; o <<= 1) {
      sv += __shfl_xor(sv, o);
      sm += __shfl_xor(sm, o);
      sd += __shfl_xor(sd, o);
    }
    if (lane == 0) {
      float dist = sd / (fmaxf(sqrtf(sv), 1e-8f) * fmaxf(sqrtf(sm), 1e-8f));
      obj[b] = 1.0f - dist;
    }
  }
}

// ---------------------------------------------------------------------------
// pos[b] = dot(g[b], a[cid[b]]) — one wave per row. Bit-identical to the
// d_logit element the reference gathers (same bf16 inputs, fp32 dot).
__global__ __launch_bounds__(256) void pos_kernel(
    const __bf16* __restrict__ g, const __bf16* __restrict__ a,
    const int* __restrict__ cid, float* __restrict__ pos) {
  int wid = threadIdx.x >> 6, lane = threadIdx.x & 63;
  int b = blockIdx.x * 4 + wid;
  if (b >= B_N) return;
  int label = cid[b];
  bf16x8 gv = *(const bf16x8*)(g + (size_t)b * D_N + lane * 8);
  bf16x8 av = *(const bf16x8*)(a + (size_t)label * D_N + lane * 8);
  float s = 0.0f;
  for (int j = 0; j < 8; ++j) s += (float)gv[j] * (float)av[j];
  for (int o = 1; o < 64; o <<= 1) s += __shfl_xor(s, o);
  if (lane == 0) pos[b] = s;
}

// ---------------------------------------------------------------------------
// NOTE: pos[b] computed by pos_kernel uses a plain fp32 dot of the same bf16
// vectors; the MFMA accumulates the identical products in fp32, so the two
// agree to fp32 rounding — far inside the 0.289 tolerance.
// Fused cosine-GEMM + exp row-sum: den[b] += sum_m exp(dot(g[b], a[m])).
// 128x128 tile, K=512 in steps of 32, global_load_lds width-16 staging,
// mfma_f32_16x16x32_bf16, 2x2 waves each computing 64x64 (4x4 MFMA tiles).
// Epilogue slim: exp + mask + 4-step shfl + 1 atomic per row per wave
// (25 adders per address — low contention). cid/pos gathers removed.
__global__ __launch_bounds__(256) void nce_gemm_kernel(
    const __bf16* __restrict__ g, const __bf16* __restrict__ a,
    float* __restrict__ den) {
  __shared__ __bf16 As[128 * 32];
  __shared__ __bf16 Bs[128 * 32];
  const int t = threadIdx.x;
  const int brow0 = blockIdx.y * 128;
  const int mrow0 = blockIdx.x * 128;
  const int lane = t & 63;
  const int wid = t >> 6;
  const int wrow = wid >> 1;      // 0..1
  const int wcol = wid & 1;       // 0..1
  const int r = lane & 15;
  const int quad = lane >> 4;

  f32x4 acc[4][4];
  for (int i = 0; i < 4; ++i)
    for (int j = 0; j < 4; ++j)
      acc[i][j] = f32x4{0.f, 0.f, 0.f, 0.f};

  for (int k0 = 0; k0 < D_N; k0 += 32) {
    __syncthreads();
    for (int i = 0; i < 2; ++i) {
      int s = t + i * 256;
      int row = s >> 2;
      int kq = (s & 3) << 3;
      const __bf16* ga = g + (size_t)(brow0 + row) * D_N + (k0 + kq);
      __builtin_amdgcn_global_load_lds((const GLOBAL_AS void*)ga,
                                       (LDS_AS void*)(As + s * 8), 16, 0, 0);
      const __bf16* gb = a + (size_t)(mrow0 + row) * D_N + (k0 + kq);
      __builtin_amdgcn_global_load_lds((const GLOBAL_AS void*)gb,
                                       (LDS_AS void*)(Bs + s * 8), 16, 0, 0);
    }
    __syncthreads();
    bf16x8 af[4], bf[4];
    for (int i = 0; i < 4; ++i)
      af[i] = *(const bf16x8*)(As + (wrow * 64 + i * 16 + r) * 32 + quad * 8);
    for (int j = 0; j < 4; ++j)
      bf[j] = *(const bf16x8*)(Bs + (wcol * 64 + j * 16 + r) * 32 + quad * 8);
    for (int i = 0; i < 4; ++i)
      for (int j = 0; j < 4; ++j)
        acc[i][j] = __builtin_amdgcn_mfma_f32_16x16x32_bf16(af[i], bf[j],
                                                            acc[i][j], 0, 0, 0);
  }

  // C/D layout: col = lane&15, row = quad*4 + reg.
  for (int i = 0; i < 4; ++i) {
    for (int reg = 0; reg < 4; ++reg) {
      float s = 0.0f;
      for (int j = 0; j < 4; ++j) {
        int m = mrow0 + wcol * 64 + j * 16 + r;
        if (m < M_N) s += __expf(acc[i][j][reg]);
      }
      s += __shfl_xor(s, 1);
      s += __shfl_xor(s, 2);
      s += __shfl_xor(s, 4);
      s += __shfl_xor(s, 8);
      if (r == 0) {
        int b = brow0 + wrow * 64 + i * 16 + quad * 4 + reg;
        atomicAdd(den + b, s);
      }
    }
  }
}

// ---------------------------------------------------------------------------
// Cross-entropy, one block per row pair (lq row b, lr row b).
// Round-3 lesson: register-scheduled loads get serialized by the compiler
// (VGPR_Count=20 proved it) -> 1.4 TB/s latency-bound. Fix: stage both rows
// via global_load_lds DMA — no register results, scheduler CANNOT serialize;
// ~25 KB per block goes in flight back-to-back. Rows are 3129 floats, base
// 4B-aligned only; load from the 16B-aligned floor covering 3136 floats and
// mask elements p outside [mis, mis+3129) at consume time.
#define CE_CHUNKS 784   // 16B chunks per row buffer (3136 floats)

__global__ __launch_bounds__(256) void ce_kernel(
    const float* __restrict__ lq, const float* __restrict__ lr,
    const int* __restrict__ cid,
    float* __restrict__ ce_q, float* __restrict__ ce_r) {
  __shared__ float Lq[CE_CHUNKS * 4];
  __shared__ float Lr[CE_CHUNKS * 4];
  const int b = blockIdx.x;
  const int t = threadIdx.x;
  const size_t start = ((size_t)b * M_N) & ~(size_t)3;  // aligned elem start
  const int mis = b & 3;                                 // (b*3129)%4 == b%4
  const size_t TOTAL = (size_t)B_N * M_N;

  // Stage: chunks c = t, t+256, t+512 (767 max < 784) + t+768 for t<16.
  // Clamp the global address for the final row's tail over-read (LDS content
  // there is junk but masked at consume).
#pragma unroll
  for (int k = 0; k < 3; ++k) {
    int c = t + k * 256;
    size_t gi = start + (size_t)c * 4;
    if (gi + 4 > TOTAL) gi = TOTAL - 4;
    __builtin_amdgcn_global_load_lds((const GLOBAL_AS void*)(lq + gi),
                                     (LDS_AS void*)(Lq + c * 4), 16, 0, 0);
    __builtin_amdgcn_global_load_lds((const GLOBAL_AS void*)(lr + gi),
                                     (LDS_AS void*)(Lr + c * 4), 16, 0, 0);
  }
  if (t < CE_CHUNKS - 768) {
    int c = t + 768;
    size_t gi = start + (size_t)c * 4;
    if (gi + 4 > TOTAL) gi = TOTAL - 4;
    __builtin_amdgcn_global_load_lds((const GLOBAL_AS void*)(lq + gi),
                                     (LDS_AS void*)(Lq + c * 4), 16, 0, 0);
    __builtin_amdgcn_global_load_lds((const GLOBAL_AS void*)(lr + gi),
                                     (LDS_AS void*)(Lr + c * 4), 16, 0, 0);
  }
  __syncthreads();  // vmcnt(0) drain + barrier: LDS visible to all

  const int lo = mis, hi = mis + M_N;
  float sq = 0.0f, sr = 0.0f;
#pragma unroll
  for (int k = 0; k < 4; ++k) {
    int c = t + k * 256;
    if (c < CE_CHUNKS) {
      float4 q = *(const float4*)(Lq + c * 4);
      float4 p = *(const float4*)(Lr + c * 4);
      int e = c * 4;
      if (e + 0 >= lo && e + 0 < hi) { sq += __expf(q.x); sr += __expf(p.x); }
      if (e + 1 >= lo && e + 1 < hi) { sq += __expf(q.y); sr += __expf(p.y); }
      if (e + 2 >= lo && e + 2 < hi) { sq += __expf(q.z); sr += __expf(p.z); }
      if (e + 3 >= lo && e + 3 < hi) { sq += __expf(q.w); sr += __expf(p.w); }
    }
  }
  for (int o = 1; o < 64; o <<= 1) {
    sq += __shfl_xor(sq, o);
    sr += __shfl_xor(sr, o);
  }
  __shared__ float ssq[4], ssr[4];
  int wid = t >> 6;
  if ((t & 63) == 0) { ssq[wid] = sq; ssr[wid] = sr; }
  __syncthreads();
  if (t == 0) {
    float tq = ssq[0] + ssq[1] + ssq[2] + ssq[3];
    float tr = ssr[0] + ssr[1] + ssr[2] + ssr[3];
    int label = cid[b];
    ce_q[b] = logf(tq) - Lq[mis + label];
    ce_r[b] = logf(tr) - Lr[mis + label];
  }
}

// ---------------------------------------------------------------------------
// Stage 1: 32 blocks reduce the per-row arrays into acc[0..3] via atomics
// (32 adders per address — negligible). acc must be pre-zeroed.
__global__ __launch_bounds__(256) void final_reduce_kernel(
    const float* __restrict__ den, const float* __restrict__ pos,
    const float* __restrict__ ce_q, const float* __restrict__ ce_r,
    const float* __restrict__ obj, float* __restrict__ acc) {
  int b = blockIdx.x * 256 + threadIdx.x;  // 32*256 == B_N exactly
  float s_nce = logf(den[b]) - pos[b];
  float s_ceq = ce_q[b];
  float s_cer = ce_r[b];
  float s_obj = obj[b];
  for (int o = 1; o < 64; o <<= 1) {
    s_nce += __shfl_xor(s_nce, o);
    s_ceq += __shfl_xor(s_ceq, o);
    s_cer += __shfl_xor(s_cer, o);
    s_obj += __shfl_xor(s_obj, o);
  }
  __shared__ float red[4][4];
  int wid = threadIdx.x >> 6;
  if ((threadIdx.x & 63) == 0) {
    red[wid][0] = s_nce; red[wid][1] = s_ceq;
    red[wid][2] = s_cer; red[wid][3] = s_obj;
  }
  __syncthreads();
  if (threadIdx.x < 4) {
    float v = red[0][threadIdx.x] + red[1][threadIdx.x]
            + red[2][threadIdx.x] + red[3][threadIdx.x];
    atomicAdd(acc + threadIdx.x, v);
  }
}

// Stage 2: combine.
__global__ void final_combine_kernel(const float* __restrict__ acc,
                                     float* __restrict__ out) {
  if (threadIdx.x == 0) {
    float nce = acc[0] / (float)B_N;
    float ceq = acc[1] / (float)B_N;
    float cer = acc[2] / (float)B_N;
    float ob  = acc[3] / (float)B_N;
    float fusion = (cer + ob + nce) * (1.0f / 3.0f);
    out[0] = fusion + ceq;  // question_loss_weight = 1.0
    out[1] = fusion;
    out[2] = ceq;
  }
}

// ---------------------------------------------------------------------------
extern "C" void kernel_launch(void* const* d_in, const int* in_sizes, int n_in,
                              void* d_out, int out_size, void* d_ws, size_t ws_size,
                              hipStream_t stream) {
  const float* mm_proj     = (const float*)d_in[0];
  const float* ans_emb     = (const float*)d_in[1];
  const float* v_max       = (const float*)d_in[2];
  const float* mm          = (const float*)d_in[3];
  const float* logits_q    = (const float*)d_in[4];
  const float* logits_rubi = (const float*)d_in[5];
  const int*   cid         = (const int*)d_in[6];
  float* out = (float*)d_out;

  // Workspace layout (16B-aligned):
  //   g_bf16 : 8192*512*2 = 8,388,608 B
  //   a_bf16 : 3200*512*2 = 3,276,800 B
  //   den[8192], acc[4], pos[8192], ce_q[8192], ce_r[8192], obj[8192]
  char* ws = (char*)d_ws;
  __bf16* g = (__bf16*)ws;
  __bf16* a = (__bf16*)(ws + 8388608);
  float* den  = (float*)(ws + 8388608 + 3276800);
  float* acc  = den + B_N;
  float* pos  = acc + 4;
  float* ce_q = pos + B_N;
  float* ce_r = ce_q + B_N;
  float* obj  = ce_r + B_N;

  // den + acc accumulate via atomics — zero them (ws is 0xAA-poisoned).
  hipMemsetAsync(den, 0, (size_t)(B_N + 4) * sizeof(float), stream);

  prep_kernel<<<PREP_G_BLOCKS + PREP_A_BLOCKS + PREP_OBJ_BLOCKS, 256, 0,
                stream>>>(mm_proj, ans_emb, v_max, mm, g, a, obj);
  pos_kernel<<<B_N / 4, 256, 0, stream>>>(g, a, cid, pos);
  nce_gemm_kernel<<<dim3(M_PAD / 128, B_N / 128), 256, 0, stream>>>(g, a, den);
  ce_kernel<<<B_N, 256, 0, stream>>>(logits_q, logits_rubi, cid, ce_q, ce_r);
  final_reduce_kernel<<<B_N / 256, 256, 0, stream>>>(den, pos, ce_q, ce_r,
                                                     obj, acc);
  final_combine_kernel<<<1, 64, 0, stream>>>(acc, out);
}